// Round 1
// baseline (211.268 us; speedup 1.0000x reference)
//
#include <hip/hip_runtime.h>
#include <hip/hip_bf16.h>

typedef unsigned short u16;
typedef unsigned int   u32;
typedef short  short8 __attribute__((ext_vector_type(8)));
typedef float  f32x4  __attribute__((ext_vector_type(4)));

#define NB   65536
#define ROWS 64
#define XP   136
#define OFF1 ((size_t)NB * 128)
#define OFF2 (OFF1 + (size_t)NB * 4)

__device__ __forceinline__ u16 f2bf(float f) {
  union { float f; u32 u; } v; v.f = f;
  return (u16)((v.u + 0x7FFFu + ((v.u >> 16) & 1u)) >> 16);
}
__device__ __forceinline__ float bf2f(u32 bits16) {
  union { u32 u; float f; } v; v.u = bits16 << 16; return v.f;
}
__device__ __forceinline__ u32 pk2(float a, float b) {
  return (u32)f2bf(a) | ((u32)f2bf(b) << 16);
}

// ---------------- weight pre-pack: 10 x [128][128] fp32 -> bf16 MFMA-B-fragment order
// packed[t]: t = w*16384 + nt*2048 + kt*512 + lane*8 + j
//   holds W_w[kt*32 + (lane>>4)*8 + j][nt*16 + (lane&15)]
__global__ void pack_w(const float* __restrict__ proj_w,
                       const float* __restrict__ in_proj_w,
                       const float* __restrict__ out_w,
                       const float* __restrict__ gate_w,
                       u16* __restrict__ wp) {
  int t = blockIdx.x * 256 + threadIdx.x;
  if (t >= 10 * 16384) return;
  int w = t >> 14, i = t & 16383;
  int nt = i >> 11, kt = (i >> 9) & 3, ln = (i >> 3) & 63, j = i & 7;
  int k = kt * 32 + ((ln >> 4) << 3) + j;
  int n = (nt << 4) + (ln & 15);
  float v;
  if (w < 4)       v = proj_w[((size_t)w << 14) + (k << 7) + n];     // proj_w[s][k][n]
  else if (w < 7)  v = in_proj_w[k * 384 + ((w - 4) << 7) + n];      // wq/wk/wv
  else if (w == 7) v = out_w[(k << 7) + n];
  else             v = gate_w[(((w - 8) << 7) + k) * 128 + n];       // gate_w rows 0:128 / 128:256
  wp[t] = f2bf(v);
}

// B fragment load (packed)
__device__ __forceinline__ short8 bfrag(const u16* __restrict__ wp, int w, int nt, int kt, int lane) {
  return *(const short8*)(wp + ((size_t)w << 14) + (size_t)((((nt << 2) + kt) << 6) + lane) * 8);
}

struct AF { short8 a[4]; };
__device__ __forceinline__ AF loadA(const u16 (*Ab)[XP], int row, int lgrp) {
  AF r;
  #pragma unroll
  for (int kt = 0; kt < 4; ++kt)
    r.a[kt] = *(const short8*)&Ab[row][kt * 32 + (lgrp << 3)];
  return r;
}
__device__ __forceinline__ f32x4 mmK128(const AF& A, const u16* __restrict__ wp, int w,
                                        int nt, int lane, float bias) {
  f32x4 acc = {bias, bias, bias, bias};
  #pragma unroll
  for (int kt = 0; kt < 4; ++kt)
    acc = __builtin_amdgcn_mfma_f32_16x16x32_bf16(A.a[kt], bfrag(wp, w, nt, kt, lane), acc, 0, 0, 0);
  return acc;
}

__global__ __launch_bounds__(256) void fused_k(
    const float* __restrict__ h0, const float* __restrict__ h1,
    const float* __restrict__ h2, const float* __restrict__ h3,
    const u16* __restrict__ wp,
    const float* __restrict__ proj_b, const float* __restrict__ ctx_w,
    const float* __restrict__ in_proj_b, const float* __restrict__ out_b,
    const float* __restrict__ gate_b, const float* __restrict__ pool_w,
    const float* __restrict__ ln_g, const float* __restrict__ ln_b,
    float* __restrict__ out) {
  __shared__ __align__(16) u16 xls[4][ROWS][XP];  // x, later normalized fused
  __shared__ __align__(16) u16 aux[ROWS][XP];     // h_s stage -> context -> o -> g
  __shared__ __align__(16) u16 aob[ROWS][XP];     // q -> attn_out
  __shared__ float lgt[4][ROWS];                  // ctx logits -> cw
  __shared__ float scf[4][ROWS][4];               // scores -> attn ; later pool partials
  __shared__ float lnr[ROWS][4][2];               // LN partials
  __shared__ float lgp[4][ROWS];                  // pool logits -> pw
  __shared__ float lnw[3][128];                   // pool_w, ln_g, ln_b

  const int tid  = threadIdx.x;
  const int lane = tid & 63;
  const int wr   = (tid >> 6) << 4;   // wave row base (16 rows per wave)
  const int r0   = blockIdx.x * ROWS;
  const int lrow = lane & 15;         // A row offset / C col offset
  const int lgrp = lane >> 4;
  const int crow0 = lgrp << 2;        // C row base

  if (tid < 128) { lnw[0][tid] = pool_w[tid]; lnw[1][tid] = ln_g[tid]; lnw[2][tid] = ln_b[tid]; }

  const float* hp[4] = {h0, h1, h2, h3};

  // ---- phase 0/1: per-source proj GEMM x_s = h_s @ proj_w[s] + proj_b[s], ctx logits
  #pragma unroll
  for (int s = 0; s < 4; ++s) {
    const float* __restrict__ hs = hp[s];
    #pragma unroll
    for (int i = 0; i < 8; ++i) {
      int f4 = i * 256 + tid;
      int row = f4 >> 5, c0 = (f4 & 31) << 2;
      const float4 v = *(const float4*)(hs + ((size_t)(r0 + row) << 7) + c0);
      *(uint2*)&aux[row][c0] = make_uint2(pk2(v.x, v.y), pk2(v.z, v.w));
    }
    __syncthreads();
    AF A = loadA(aux, wr + lrow, lgrp);
    float lp0 = 0, lp1 = 0, lp2 = 0, lp3 = 0;
    #pragma unroll
    for (int nt = 0; nt < 8; ++nt) {
      int n = (nt << 4) + lrow;
      f32x4 acc = mmK128(A, wp, s, nt, lane, proj_b[(s << 7) + n]);
      float cwn = ctx_w[n];
      lp0 += acc[0] * cwn; lp1 += acc[1] * cwn; lp2 += acc[2] * cwn; lp3 += acc[3] * cwn;
      xls[s][wr + crow0 + 0][n] = f2bf(acc[0]);
      xls[s][wr + crow0 + 1][n] = f2bf(acc[1]);
      xls[s][wr + crow0 + 2][n] = f2bf(acc[2]);
      xls[s][wr + crow0 + 3][n] = f2bf(acc[3]);
    }
    #pragma unroll
    for (int m = 1; m < 16; m <<= 1) {
      lp0 += __shfl_xor(lp0, m); lp1 += __shfl_xor(lp1, m);
      lp2 += __shfl_xor(lp2, m); lp3 += __shfl_xor(lp3, m);
    }
    if (lrow == 0) {
      lgt[s][wr + crow0 + 0] = lp0; lgt[s][wr + crow0 + 1] = lp1;
      lgt[s][wr + crow0 + 2] = lp2; lgt[s][wr + crow0 + 3] = lp3;
    }
    __syncthreads();
  }

  // ---- phase 2: ctx softmax over s (ctx_b cancels)
  if (tid < ROWS) {
    float l0 = lgt[0][tid], l1 = lgt[1][tid], l2 = lgt[2][tid], l3 = lgt[3][tid];
    float mx = fmaxf(fmaxf(l0, l1), fmaxf(l2, l3));
    float e0 = __expf(l0 - mx), e1 = __expf(l1 - mx), e2 = __expf(l2 - mx), e3 = __expf(l3 - mx);
    float inv = 1.f / (e0 + e1 + e2 + e3);
    lgt[0][tid] = e0 * inv; lgt[1][tid] = e1 * inv; lgt[2][tid] = e2 * inv; lgt[3][tid] = e3 * inv;
  }
  __syncthreads();

  // ---- phase 3: context = sum_s cw[s] * x_s  -> aux
  #pragma unroll
  for (int i = 0; i < 8; ++i) {
    int e4 = i * 256 + tid;
    int row = e4 >> 5, c0 = (e4 & 31) << 2;
    float c0v = 0, c1v = 0, c2v = 0, c3v = 0;
    #pragma unroll
    for (int s = 0; s < 4; ++s) {
      float cw = lgt[s][row];
      uint2 d = *(const uint2*)&xls[s][row][c0];
      c0v += cw * bf2f(d.x & 0xffff); c1v += cw * bf2f(d.x >> 16);
      c2v += cw * bf2f(d.y & 0xffff); c3v += cw * bf2f(d.y >> 16);
    }
    *(uint2*)&aux[row][c0] = make_uint2(pk2(c0v, c1v), pk2(c2v, c3v));
  }
  __syncthreads();

  // ---- phase 4: q = context @ wq + bq -> aob
  {
    AF A = loadA(aux, wr + lrow, lgrp);
    #pragma unroll
    for (int nt = 0; nt < 8; ++nt) {
      int n = (nt << 4) + lrow;
      f32x4 acc = mmK128(A, wp, 4, nt, lane, in_proj_b[n]);
      #pragma unroll
      for (int j = 0; j < 4; ++j) aob[wr + crow0 + j][n] = f2bf(acc[j]);
    }
  }
  __syncthreads();

  // ---- phase 5: k_s = x_s @ wk + bk ; scores[s][row][h] = q . k (per 32-wide head)
  #pragma unroll
  for (int s = 0; s < 4; ++s) {
    float sc[4][4] = {};
    AF A = loadA(xls[s], wr + lrow, lgrp);
    #pragma unroll
    for (int nt = 0; nt < 8; ++nt) {
      int n = (nt << 4) + lrow;
      f32x4 acc = mmK128(A, wp, 5, nt, lane, in_proj_b[128 + n]);
      #pragma unroll
      for (int j = 0; j < 4; ++j)
        sc[j][nt >> 1] += acc[j] * bf2f((u32)aob[wr + crow0 + j][n]);
    }
    #pragma unroll
    for (int m = 1; m < 16; m <<= 1)
      #pragma unroll
      for (int j = 0; j < 4; ++j)
        #pragma unroll
        for (int h = 0; h < 4; ++h)
          sc[j][h] += __shfl_xor(sc[j][h], m);
    #pragma unroll
    for (int h = 0; h < 4; ++h)
      if (lrow == h) {
        #pragma unroll
        for (int j = 0; j < 4; ++j) scf[s][wr + crow0 + j][h] = sc[j][h];
      }
  }
  __syncthreads();

  // ---- phase 5b: attention softmax over s + attn_weights output
  {
    int row = tid >> 2, h = tid & 3;
    const float scale = 0.17677669529663687f;  // 1/sqrt(32)
    float l0 = scf[0][row][h] * scale, l1 = scf[1][row][h] * scale;
    float l2 = scf[2][row][h] * scale, l3 = scf[3][row][h] * scale;
    float mx = fmaxf(fmaxf(l0, l1), fmaxf(l2, l3));
    float e0 = __expf(l0 - mx), e1 = __expf(l1 - mx), e2 = __expf(l2 - mx), e3 = __expf(l3 - mx);
    float inv = 1.f / (e0 + e1 + e2 + e3);
    scf[0][row][h] = e0 * inv; scf[1][row][h] = e1 * inv;
    scf[2][row][h] = e2 * inv; scf[3][row][h] = e3 * inv;
  }
  __syncthreads();
  {
    int row = tid >> 2, s = tid & 3;
    float m = 0.25f * (scf[s][row][0] + scf[s][row][1] + scf[s][row][2] + scf[s][row][3]);
    out[OFF1 + ((size_t)(r0 + row) << 2) + s] = m;
  }

  // ---- phase 6: v_s = x_s @ wv + bv ; o = sum_s attn * v_s -> aux
  {
    float oa[8][4] = {};
    #pragma unroll
    for (int s = 0; s < 4; ++s) {
      AF A = loadA(xls[s], wr + lrow, lgrp);
      float aw[4][4];
      #pragma unroll
      for (int j = 0; j < 4; ++j)
        #pragma unroll
        for (int h = 0; h < 4; ++h) aw[j][h] = scf[s][wr + crow0 + j][h];
      #pragma unroll
      for (int nt = 0; nt < 8; ++nt) {
        int n = (nt << 4) + lrow;
        f32x4 acc = mmK128(A, wp, 6, nt, lane, in_proj_b[256 + n]);
        #pragma unroll
        for (int j = 0; j < 4; ++j) oa[nt][j] += aw[j][nt >> 1] * acc[j];
      }
    }
    #pragma unroll
    for (int nt = 0; nt < 8; ++nt) {
      int n = (nt << 4) + lrow;
      #pragma unroll
      for (int j = 0; j < 4; ++j) aux[wr + crow0 + j][n] = f2bf(oa[nt][j]);
    }
  }
  __syncthreads();

  // ---- phase 7: attn_out = o @ out_w + out_b -> aob
  {
    AF A = loadA(aux, wr + lrow, lgrp);
    #pragma unroll
    for (int nt = 0; nt < 8; ++nt) {
      int n = (nt << 4) + lrow;
      f32x4 acc = mmK128(A, wp, 7, nt, lane, out_b[n]);
      #pragma unroll
      for (int j = 0; j < 4; ++j) aob[wr + crow0 + j][n] = f2bf(acc[j]);
    }
  }
  __syncthreads();

  // ---- phase 8 per s: gate GEMM + sigmoid (output g) + fuse + LN + pool logit
  #pragma unroll 1
  for (int s = 0; s < 4; ++s) {
    {
      AF Ax = loadA(xls[s], wr + lrow, lgrp);
      AF Aa = loadA(aob, wr + lrow, lgrp);
      #pragma unroll
      for (int nt = 0; nt < 8; ++nt) {
        int n = (nt << 4) + lrow;
        float b = gate_b[n];
        f32x4 acc = {b, b, b, b};
        #pragma unroll
        for (int kt = 0; kt < 4; ++kt)
          acc = __builtin_amdgcn_mfma_f32_16x16x32_bf16(Ax.a[kt], bfrag(wp, 8, nt, kt, lane), acc, 0, 0, 0);
        #pragma unroll
        for (int kt = 0; kt < 4; ++kt)
          acc = __builtin_amdgcn_mfma_f32_16x16x32_bf16(Aa.a[kt], bfrag(wp, 9, nt, kt, lane), acc, 0, 0, 0);
        #pragma unroll
        for (int j = 0; j < 4; ++j) {
          float g = 1.f / (1.f + __expf(-acc[j]));
          out[OFF2 + (((size_t)(r0 + wr + crow0 + j) << 2) + s) * 128 + n] = g;
          aux[wr + crow0 + j][n] = f2bf(g);
        }
      }
    }
    __syncthreads();
    int row = tid >> 2, p = tid & 3, e0 = (tid & 3) << 5;
    float sum = 0, ss = 0;
    #pragma unroll
    for (int c = 0; c < 8; ++c) {
      int e = e0 + (c << 2);
      uint2 gd = *(const uint2*)&aux[row][e];
      uint2 ad = *(const uint2*)&aob[row][e];
      uint2 xd = *(const uint2*)&xls[s][row][e];
      float g0 = bf2f(gd.x & 0xffff), g1 = bf2f(gd.x >> 16), g2 = bf2f(gd.y & 0xffff), g3 = bf2f(gd.y >> 16);
      float a0 = bf2f(ad.x & 0xffff), a1 = bf2f(ad.x >> 16), a2 = bf2f(ad.y & 0xffff), a3 = bf2f(ad.y >> 16);
      float x0 = bf2f(xd.x & 0xffff), x1 = bf2f(xd.x >> 16), x2 = bf2f(xd.y & 0xffff), x3 = bf2f(xd.y >> 16);
      float f0 = g0 * a0 + (1.f - g0) * x0, f1 = g1 * a1 + (1.f - g1) * x1;
      float f2 = g2 * a2 + (1.f - g2) * x2, f3 = g3 * a3 + (1.f - g3) * x3;
      sum += f0 + f1 + f2 + f3;
      ss  += f0 * f0 + f1 * f1 + f2 * f2 + f3 * f3;
      *(uint2*)&xls[s][row][e] = make_uint2(pk2(f0, f1), pk2(f2, f3));
    }
    lnr[row][p][0] = sum; lnr[row][p][1] = ss;
    __syncthreads();
    float ts  = lnr[row][0][0] + lnr[row][1][0] + lnr[row][2][0] + lnr[row][3][0];
    float tss = lnr[row][0][1] + lnr[row][1][1] + lnr[row][2][1] + lnr[row][3][1];
    float mean = ts * 0.0078125f;
    float var  = tss * 0.0078125f - mean * mean;
    float rstd = rsqrtf(var + 1e-5f);
    float pp = 0;
    #pragma unroll
    for (int c = 0; c < 8; ++c) {
      int e = e0 + (c << 2);
      uint2 fd = *(const uint2*)&xls[s][row][e];
      float f0 = bf2f(fd.x & 0xffff), f1 = bf2f(fd.x >> 16), f2 = bf2f(fd.y & 0xffff), f3 = bf2f(fd.y >> 16);
      f0 = (f0 - mean) * rstd * lnw[1][e + 0] + lnw[2][e + 0];
      f1 = (f1 - mean) * rstd * lnw[1][e + 1] + lnw[2][e + 1];
      f2 = (f2 - mean) * rstd * lnw[1][e + 2] + lnw[2][e + 2];
      f3 = (f3 - mean) * rstd * lnw[1][e + 3] + lnw[2][e + 3];
      pp += f0 * lnw[0][e] + f1 * lnw[0][e + 1] + f2 * lnw[0][e + 2] + f3 * lnw[0][e + 3];
      *(uint2*)&xls[s][row][e] = make_uint2(pk2(f0, f1), pk2(f2, f3));
    }
    scf[0][row][p] = pp;   // scf dead here; reuse as pool-partial scratch
    __syncthreads();
    if (p == 0)
      lgp[s][row] = scf[0][row][0] + scf[0][row][1] + scf[0][row][2] + scf[0][row][3];
    __syncthreads();
  }

  // ---- phase 9: pool softmax (pool_b cancels) + pooled output
  if (tid < ROWS) {
    float l0 = lgp[0][tid], l1 = lgp[1][tid], l2 = lgp[2][tid], l3 = lgp[3][tid];
    float mx = fmaxf(fmaxf(l0, l1), fmaxf(l2, l3));
    float e0 = __expf(l0 - mx), e1 = __expf(l1 - mx), e2 = __expf(l2 - mx), e3 = __expf(l3 - mx);
    float inv = 1.f / (e0 + e1 + e2 + e3);
    lgp[0][tid] = e0 * inv; lgp[1][tid] = e1 * inv; lgp[2][tid] = e2 * inv; lgp[3][tid] = e3 * inv;
  }
  __syncthreads();
  #pragma unroll
  for (int i = 0; i < 8; ++i) {
    int e4 = i * 256 + tid;
    int row = e4 >> 5, c0 = (e4 & 31) << 2;
    float p0 = lgp[0][row], p1 = lgp[1][row], p2 = lgp[2][row], p3 = lgp[3][row];
    float r0v = 0, r1v = 0, r2v = 0, r3v = 0;
    #pragma unroll
    for (int s = 0; s < 4; ++s) {
      float pw = (s == 0) ? p0 : (s == 1) ? p1 : (s == 2) ? p2 : p3;
      uint2 d = *(const uint2*)&xls[s][row][c0];
      r0v += pw * bf2f(d.x & 0xffff); r1v += pw * bf2f(d.x >> 16);
      r2v += pw * bf2f(d.y & 0xffff); r3v += pw * bf2f(d.y >> 16);
    }
    float4 o4; o4.x = r0v; o4.y = r1v; o4.z = r2v; o4.w = r3v;
    *(float4*)(out + ((size_t)(r0 + row) << 7) + c0) = o4;
  }
}

extern "C" void kernel_launch(void* const* d_in, const int* in_sizes, int n_in,
                              void* d_out, int out_size, void* d_ws, size_t ws_size,
                              hipStream_t stream) {
  const float* h0        = (const float*)d_in[0];
  const float* h1        = (const float*)d_in[1];
  const float* h2        = (const float*)d_in[2];
  const float* h3        = (const float*)d_in[3];
  const float* proj_w    = (const float*)d_in[4];
  const float* proj_b    = (const float*)d_in[5];
  const float* ctx_w     = (const float*)d_in[6];
  const float* in_proj_w = (const float*)d_in[8];
  const float* in_proj_b = (const float*)d_in[9];
  const float* out_w     = (const float*)d_in[10];
  const float* out_b     = (const float*)d_in[11];
  const float* gate_w    = (const float*)d_in[12];
  const float* gate_b    = (const float*)d_in[13];
  const float* pool_w    = (const float*)d_in[14];
  const float* ln_g      = (const float*)d_in[16];
  const float* ln_b      = (const float*)d_in[17];
  u16* wp = (u16*)d_ws;

  pack_w<<<640, 256, 0, stream>>>(proj_w, in_proj_w, out_w, gate_w, wp);
  fused_k<<<NB / ROWS, 256, 0, stream>>>(h0, h1, h2, h3, wp,
                                         proj_b, ctx_w, in_proj_b, out_b, gate_b,
                                         pool_w, ln_g, ln_b, (float*)d_out);
}